// Round 3
// baseline (145.568 us; speedup 1.0000x reference)
//
#include <hip/hip_runtime.h>

// Cross_LocalAttention: windowed attention + LePE depthwise conv.
// B=8, H=W=128, DIM=256, HEADS=8, HD=32, window 8x8 (WS=64).
// One block (256 threads, 4 waves) per (window, head): 16384 blocks.
// Swapped-operand QK^T (mfma(K,Q)) puts a full P-row in each lane; the V
// token permutation sp() makes the PV A-frag a pure intra-lane repack.
// Plain bf16 q/k (score err ~1e-2 max, budget 6e-2). Conv reads packed
// channel-pairs (c, c+16) so one ds_read_b32 feeds both output halves.
// Single __syncthreads per block; conv fused into the epilogue.

#define SCALE_F 0.17677669529663687f  // 32^-0.5

typedef __attribute__((ext_vector_type(8))) short bf16x8;
typedef __attribute__((ext_vector_type(4))) float f32x4;
typedef __attribute__((ext_vector_type(4))) unsigned int u32x4;

static __device__ __forceinline__ unsigned short f2bf(float f) {  // RNE
    unsigned u = __builtin_bit_cast(unsigned, f);
    u += 0x7fffu + ((u >> 16) & 1u);
    return (unsigned short)(u >> 16);
}
static __device__ __forceinline__ float bf2f_lo(unsigned u) {  // low half
    return __builtin_bit_cast(float, u << 16);
}
static __device__ __forceinline__ float bf2f_hi(unsigned u) {  // high half
    return __builtin_bit_cast(float, u & 0xffff0000u);
}

__global__ __launch_bounds__(256, 6) void lepe_attn_kernel(
    const float* __restrict__ qkv,
    const float* __restrict__ lw,
    const float* __restrict__ lb,
    float* __restrict__ out)
{
    const int bid  = blockIdx.x;
    const int head = bid & 7;
    const int win  = bid >> 3;
    const int ww   = win & 15;
    const int wh   = (win >> 4) & 15;
    const int b    = win >> 8;
    const int t    = threadIdx.x;

    // LDS: 20.7 KB. Row strides keep b128 reads 16B-aligned, <=2-way bank
    // aliasing (free per m136).
    __shared__ __align__(16) short q_s[64][40];
    __shared__ __align__(16) short k_s[64][40];
    __shared__ __align__(16) short v_t[32][72];      // V^T, perm'd token axis
    __shared__ __align__(16) unsigned v_pair[64][18]; // (ch c | ch c+16) packed
    __shared__ float w_s[288];
    __shared__ float b_s[32];

    const float* Qp = qkv;
    const float* Kp = qkv + (size_t)33554432;   // 8*16384*256
    const float* Vp = qkv + (size_t)67108864;
    float* xout = out;
    float* qout = out + (size_t)33554432;

    for (int i = t; i < 288; i += 256) w_s[i] = lw[head * 288 + i];
    if (t < 32) b_s[t] = lb[head * 32 + t];

    // ---- stage q,k,v
    #pragma unroll
    for (int u = 0; u < 2; ++u) {
        const int idx = t + u * 256;
        const int s   = idx >> 3;
        const int d4  = idx & 7;
        const int row = wh * 8 + (s >> 3);
        const int col = ww * 8 + (s & 7);
        const size_t goff = ((size_t)(b * 16384 + row * 128 + col)) * 256
                          + head * 32 + d4 * 4;

        float4 fq = *(const float4*)(Qp + goff);
        float4 fk = *(const float4*)(Kp + goff);
        float4 fv = *(const float4*)(Vp + goff);

        fq.x *= SCALE_F; fq.y *= SCALE_F; fq.z *= SCALE_F; fq.w *= SCALE_F;
        *(float4*)(qout + ((size_t)bid * 64 + s) * 32 + d4 * 4) = fq;

        uint2 qp, kp;
        qp.x = (unsigned)f2bf(fq.x) | ((unsigned)f2bf(fq.y) << 16);
        qp.y = (unsigned)f2bf(fq.z) | ((unsigned)f2bf(fq.w) << 16);
        kp.x = (unsigned)f2bf(fk.x) | ((unsigned)f2bf(fk.y) << 16);
        kp.y = (unsigned)f2bf(fk.z) | ((unsigned)f2bf(fk.w) << 16);
        *(uint2*)&q_s[s][d4 * 4] = qp;
        *(uint2*)&k_s[s][d4 * 4] = kp;

        // V: bf16. Permuted transpose (PV B-frag) + packed pairs (conv).
        const unsigned short b0 = f2bf(fv.x), b1 = f2bf(fv.y),
                             b2 = f2bf(fv.z), b3 = f2bf(fv.w);
        const int sp = ((s >> 1) & 1) * 32 + ((s >> 2) & 3) * 8
                     + (s & 1) * 4 + (s >> 4);
        v_t[d4 * 4 + 0][sp] = (short)b0;
        v_t[d4 * 4 + 1][sp] = (short)b1;
        v_t[d4 * 4 + 2][sp] = (short)b2;
        v_t[d4 * 4 + 3][sp] = (short)b3;
        const unsigned short vb[4] = {b0, b1, b2, b3};
        #pragma unroll
        for (int j = 0; j < 4; ++j) {
            const int ch = d4 * 4 + j;
            ((unsigned short*)&v_pair[s][ch & 15])[ch >> 4] = vb[j];
        }
    }
    __syncthreads();

    const int lane = t & 63;
    const int wid  = t >> 6;
    const int c    = lane & 15;
    const int g    = lane >> 4;
    const int i0   = wid * 16;

    // ---- QK^T swapped: S[i0+c][16jt+4g+r] in lane(c,g) reg r of tile jt
    const bf16x8 bq = *(const bf16x8*)&q_s[i0 + c][g * 8];
    f32x4 sacc[4];
    #pragma unroll
    for (int jt = 0; jt < 4; ++jt) {
        const bf16x8 ak = *(const bf16x8*)&k_s[jt * 16 + c][g * 8];
        f32x4 acc = {0.f, 0.f, 0.f, 0.f};
        sacc[jt] = __builtin_amdgcn_mfma_f32_16x16x32_bf16(ak, bq, acc, 0, 0, 0);
    }

    // ---- softmax: row i0+c spread over lanes {c, c+16, c+32, c+48}
    float mx = -3.0e38f;
    #pragma unroll
    for (int jt = 0; jt < 4; ++jt)
        #pragma unroll
        for (int r = 0; r < 4; ++r)
            mx = fmaxf(mx, sacc[jt][r]);
    mx = fmaxf(mx, __shfl_xor(mx, 16));
    mx = fmaxf(mx, __shfl_xor(mx, 32));

    float p[4][4];
    float sm = 0.f;
    #pragma unroll
    for (int jt = 0; jt < 4; ++jt)
        #pragma unroll
        for (int r = 0; r < 4; ++r) {
            p[jt][r] = __expf(sacc[jt][r] - mx);
            sm += p[jt][r];
        }
    sm += __shfl_xor(sm, 16);
    sm += __shfl_xor(sm, 32);
    const float inv = 1.0f / sm;

    // pack P rows to bf16; A-frags are intra-lane by construction of sp():
    // element e of step ks: P[i0+c][16(e&3)+4g+2ks+(e>>2)]
    unsigned dwA[4], dwB[4];
    #pragma unroll
    for (int r = 0; r < 4; ++r) {
        dwA[r] = (unsigned)f2bf(p[0][r] * inv)
               | ((unsigned)f2bf(p[1][r] * inv) << 16);
        dwB[r] = (unsigned)f2bf(p[2][r] * inv)
               | ((unsigned)f2bf(p[3][r] * inv) << 16);
    }
    const u32x4 w0 = {dwA[0], dwB[0], dwA[1], dwB[1]};
    const u32x4 w1 = {dwA[2], dwB[2], dwA[3], dwB[3]};
    const bf16x8 pa0 = __builtin_bit_cast(bf16x8, w0);
    const bf16x8 pa1 = __builtin_bit_cast(bf16x8, w1);

    // ---- PV
    f32x4 o0 = {0.f, 0.f, 0.f, 0.f};
    f32x4 o1 = {0.f, 0.f, 0.f, 0.f};
    {
        const bf16x8 vb00 = *(const bf16x8*)&v_t[c][g * 8];
        const bf16x8 vb10 = *(const bf16x8*)&v_t[16 + c][g * 8];
        const bf16x8 vb01 = *(const bf16x8*)&v_t[c][32 + g * 8];
        const bf16x8 vb11 = *(const bf16x8*)&v_t[16 + c][32 + g * 8];
        o0 = __builtin_amdgcn_mfma_f32_16x16x32_bf16(pa0, vb00, o0, 0, 0, 0);
        o1 = __builtin_amdgcn_mfma_f32_16x16x32_bf16(pa0, vb10, o1, 0, 0, 0);
        o0 = __builtin_amdgcn_mfma_f32_16x16x32_bf16(pa1, vb01, o0, 0, 0, 0);
        o1 = __builtin_amdgcn_mfma_f32_16x16x32_bf16(pa1, vb11, o1, 0, 0, 0);
    }

    // ---- fused LePE conv + epilogue.
    // Lane's 4 output tokens: s = i0+4g+r -> window row srow, cols scol0+r.
    const int srow  = 2 * wid + (g >> 1);
    const int scol0 = 4 * (g & 1);

    // gather packed patch (both halves at once): rows srow-1..+1, cols
    // scol0-1..scol0+4
    unsigned pr[3][6];
    #pragma unroll
    for (int dy = 0; dy < 3; ++dy) {
        const int rr   = srow + dy - 1;
        const bool rok = (rr >= 0) && (rr < 8);
        const int rcl  = rok ? rr : 0;
        #pragma unroll
        for (int dx = 0; dx < 6; ++dx) {
            const int cc   = scol0 + dx - 1;
            const bool cok = (cc >= 0) && (cc < 8);
            const int ccl  = cok ? cc : 0;
            const unsigned val = v_pair[rcl * 8 + ccl][c];
            pr[dy][dx] = (rok && cok) ? val : 0u;
        }
    }
    #pragma unroll
    for (int half = 0; half < 2; ++half) {
        const int ch = c + 16 * half;
        float wv[9];
        #pragma unroll
        for (int k2 = 0; k2 < 9; ++k2) wv[k2] = w_s[ch * 9 + k2];
        float acc[4] = {b_s[ch], b_s[ch], b_s[ch], b_s[ch]};
        #pragma unroll
        for (int dy = 0; dy < 3; ++dy) {
            float rowv[6];
            #pragma unroll
            for (int dx = 0; dx < 6; ++dx)
                rowv[dx] = half ? bf2f_hi(pr[dy][dx]) : bf2f_lo(pr[dy][dx]);
            #pragma unroll
            for (int r = 0; r < 4; ++r)
                #pragma unroll
                for (int dk = 0; dk < 3; ++dk)
                    acc[r] += wv[dy * 3 + dk] * rowv[r + dk];
        }
        #pragma unroll
        for (int r = 0; r < 4; ++r) {
            if (half == 0) o0[r] += acc[r]; else o1[r] += acc[r];
        }
    }

    #pragma unroll
    for (int r = 0; r < 4; ++r) {
        const int s   = i0 + 4 * g + r;
        const int row = wh * 8 + (s >> 3);
        const int col = ww * 8 + (s & 7);
        float* xo = xout + ((size_t)(b * 16384 + row * 128 + col)) * 256
                  + head * 32;
        xo[c]      = o0[r];
        xo[16 + c] = o1[r];
    }
}

extern "C" void kernel_launch(void* const* d_in, const int* in_sizes, int n_in,
                              void* d_out, int out_size, void* d_ws, size_t ws_size,
                              hipStream_t stream) {
    (void)in_sizes; (void)n_in; (void)out_size; (void)d_ws; (void)ws_size;
    const float* qkv = (const float*)d_in[0];
    const float* lw  = (const float*)d_in[1];
    const float* lb  = (const float*)d_in[2];
    float* out = (float*)d_out;
    lepe_attn_kernel<<<dim3(16384), dim3(256), 0, stream>>>(qkv, lw, lb, out);
}